// Round 4
// baseline (1243.874 us; speedup 1.0000x reference)
//
#include <hip/hip_runtime.h>

// ---------------------------------------------------------------------------
// WindowAttention fused pipeline for MI355X (gfx950)
//   B=2048 windows, N=128 tokens, C=256, H=8 heads, hd=32
// Round-4: per-(window,head) blocks (16384), 512 thr, 78.8KB LDS, 2 blk/CU.
// Phase-A k-loop software-pipelined: W frags reg-double-buffered (issue at
// kc for kc+1), x slab prefetch distance-2 with write-late staging (T14),
// native bf16 cvt, setprio around MFMA clusters.
// xcat (bf16) lives in d_out; proj GEMM runs in-place (proven path).
// ---------------------------------------------------------------------------

typedef __attribute__((ext_vector_type(8))) short     short8;
typedef __attribute__((ext_vector_type(8))) __bf16    bf16x8;
typedef __attribute__((ext_vector_type(4))) float     f32x4;

__device__ __forceinline__ unsigned short f2bf(float f) {
  return __builtin_bit_cast(unsigned short, (__bf16)f);   // native cvt, RTNE
}

__device__ __forceinline__ void gload_lds16(const void* g, void* l) {
  __builtin_amdgcn_global_load_lds((const __attribute__((address_space(1))) void*)g,
                                   (__attribute__((address_space(3))) void*)l, 16, 0, 0);
}

// ---------------- precompute kernels (~2 MB of ws) ----------------

__global__ void pos_kernel(float* __restrict__ pos_t) {
  int e = blockIdx.x * 256 + threadIdx.x;          // 32768 = 128*256
  int t = e >> 8, c = e & 255;
  int p = t & 63;                                   // tiled (1,2,1)
  const float norm = 6.28318530717958647692f / 8.000001f;  // scale/(8+1e-6)
  float yn = (float)((p >> 3) + 1) * norm;
  float xn = (float)((p & 7) + 1) * norm;
  int cc = c & 127;
  int m  = cc >> 1;
  float v = ((c < 128) ? yn : xn) * __expf(-(float)m * 0.14391156831f);
  pos_t[e] = (cc & 1) ? cosf(v) : sinf(v);
}

__global__ void posw_kernel(const float* __restrict__ pos_t,
                            const float* __restrict__ Wm,
                            float* __restrict__ posW) {
  int e = blockIdx.x * 256 + threadIdx.x;          // 98304 = 128*768
  int t = e / 768, c = e - t * 768;
  const float4* pr = (const float4*)(pos_t + t * 256);
  const float4* wr = (const float4*)(Wm + (size_t)c * 256);
  float acc = 0.f;
  #pragma unroll 8
  for (int k = 0; k < 64; ++k) {
    float4 p = pr[k], w = wr[k];
    acc += p.x * w.x + p.y * w.y + p.z * w.z + p.w * w.w;
  }
  posW[e] = acc;
}

__global__ void bias_kernel(const float* __restrict__ rpb, float* __restrict__ bias_t) {
  int e = blockIdx.x * 256 + threadIdx.x;          // 131072 = 8*128*128
  int h = e >> 14, i = (e >> 7) & 127, j = e & 127;
  int di = i >> 6, hi = (i >> 3) & 7, wi = i & 7;
  int dj = j >> 6, hj = (j >> 3) & 7, wj = j & 7;
  int idx = (di - dj + 1) * 225 + (hi - hj + 7) * 15 + (wi - wj + 7);
  bias_t[e] = rpb[idx * 8 + h];
}

__global__ void wconv_kernel(const float* __restrict__ Ws, const float* __restrict__ Wm,
                             const float* __restrict__ Wp,
                             unsigned short* __restrict__ Wsb,
                             unsigned short* __restrict__ Wmb,
                             unsigned short* __restrict__ Wpb) {
  int e = blockIdx.x * 256 + threadIdx.x;          // 524288
  if (e < 196608)       Wsb[e]          = f2bf(Ws[e]);
  else if (e < 393216)  Wmb[e - 196608] = f2bf(Wm[e - 196608]);
  else                  Wpb[e - 393216] = f2bf(Wp[e - 393216]);
}

// ---------------- fused per-(window,head) QKV + attention ----------------

__global__ __launch_bounds__(512, 4) void fused_head(
    const float* __restrict__ x,
    const unsigned short* __restrict__ Wsb,
    const unsigned short* __restrict__ Wmb,
    const float* __restrict__ posW,
    const float* __restrict__ bias_t,
    unsigned short* __restrict__ xcat)
{
  __shared__ unsigned short Qs[128 * 40];          // 10240 B
  __shared__ unsigned short Ks[128 * 40];
  __shared__ unsigned short Qm[128 * 40];
  __shared__ unsigned short Km[128 * 40];
  __shared__ unsigned short VsT[32 * 136];         // [d][token]
  __shared__ unsigned short VmT[32 * 136];
  __shared__ unsigned short PX[2 * 128 * 40];      // Phase A: x-slab dbuf; B/C: P

  // bijective swizzle: XCD = blockIdx%8 = b%8 -> all 8 heads of a window on 1 XCD
  const int kblk = blockIdx.x;
  const int b = (kblk & 7) | ((kblk >> 6) << 3);
  const int h = (kblk >> 3) & 7;

  const int tid = threadIdx.x, w = tid >> 6, lane = tid & 63;
  const int lr = lane & 15, lk = lane >> 4;
  const float scale = 0.17677669529663688f;        // 32^-0.5
  const float* xb = x + (size_t)b * 32768;

  // ======== Phase A: QKV for head h (software-pipelined k-loop) ========
  const int mh = (w >> 2) * 64;
  const int u0 = (w & 3) * 3;
  f32x4 acc[3][4];
  #pragma unroll
  for (int i = 0; i < 3; ++i)
    #pragma unroll
    for (int mt = 0; mt < 4; ++mt) acc[i][mt] = f32x4{0.f, 0.f, 0.f, 0.f};

  int uo[3], unt[3];
  const unsigned short* wbase[3];
  #pragma unroll
  for (int i = 0; i < 3; ++i) {
    int u = u0 + i;
    int o = u >> 1, nt = u & 1;
    uo[i] = o; unt[i] = nt;
    int o3 = (o < 3) ? o : o - 3;
    wbase[i] = ((o < 3) ? Wsb : Wmb)
             + (size_t)(o3 * 256 + h * 32 + nt * 16 + lr) * 256 + lk * 8;
  }

  // x slab staging: thread stages 8 f32 of row srow, cols kc*32+sc8..+7
  const int srow = tid >> 2, sc8 = (tid & 3) * 8;
  const float* xsrc = xb + srow * 256 + sc8;
  float4 xr[2][2];                                  // slot c&1 holds chunk c
  bf16x8 wf[2][3];                                  // W frag dbuf (parity-indexed)

  // prologue: issue chunk0+1 x loads, chunk0 W loads; write buf0; barrier
  xr[0][0] = *(const float4*)(xsrc);
  xr[0][1] = *(const float4*)(xsrc + 4);
  xr[1][0] = *(const float4*)(xsrc + 32);
  xr[1][1] = *(const float4*)(xsrc + 36);
  #pragma unroll
  for (int i = 0; i < 3; ++i) wf[0][i] = *(const bf16x8*)(wbase[i]);
  {
    float4 a = xr[0][0], d = xr[0][1];
    short8 o8;
    o8[0] = (short)f2bf(a.x); o8[1] = (short)f2bf(a.y);
    o8[2] = (short)f2bf(a.z); o8[3] = (short)f2bf(a.w);
    o8[4] = (short)f2bf(d.x); o8[5] = (short)f2bf(d.y);
    o8[6] = (short)f2bf(d.z); o8[7] = (short)f2bf(d.w);
    *(short8*)&PX[srow * 40 + sc8] = o8;
  }
  __syncthreads();

  #pragma unroll
  for (int kc = 0; kc < 8; ++kc) {
    // issue-early: x loads for chunk kc+2, W loads for chunk kc+1
    if (kc + 2 < 8) {
      xr[kc & 1][0] = *(const float4*)(xsrc + (kc + 2) * 32);
      xr[kc & 1][1] = *(const float4*)(xsrc + (kc + 2) * 32 + 4);
    }
    if (kc + 1 < 8) {
      #pragma unroll
      for (int i = 0; i < 3; ++i)
        wf[(kc + 1) & 1][i] = *(const bf16x8*)(wbase[i] + (kc + 1) * 32);
    }
    // compute chunk kc from buf[kc&1] with wf[kc&1] (loaded last chunk)
    bf16x8 af[4];
    #pragma unroll
    for (int mt = 0; mt < 4; ++mt)
      af[mt] = *(const bf16x8*)&PX[(kc & 1) * 5120 + (mh + mt * 16 + lr) * 40 + lk * 8];
    __builtin_amdgcn_s_setprio(1);
    #pragma unroll
    for (int i = 0; i < 3; ++i)
      #pragma unroll
      for (int mt = 0; mt < 4; ++mt)
        acc[i][mt] = __builtin_amdgcn_mfma_f32_16x16x32_bf16(af[mt], wf[kc & 1][i],
                                                             acc[i][mt], 0, 0, 0);
    __builtin_amdgcn_s_setprio(0);
    // write-late: stage chunk kc+1 (loaded at kc-1) into buf[(kc+1)&1]
    if (kc + 1 < 8) {
      float4 a = xr[(kc + 1) & 1][0], d = xr[(kc + 1) & 1][1];
      short8 o8;
      o8[0] = (short)f2bf(a.x); o8[1] = (short)f2bf(a.y);
      o8[2] = (short)f2bf(a.z); o8[3] = (short)f2bf(a.w);
      o8[4] = (short)f2bf(d.x); o8[5] = (short)f2bf(d.y);
      o8[6] = (short)f2bf(d.z); o8[7] = (short)f2bf(d.w);
      *(short8*)&PX[((kc + 1) & 1) * 5120 + srow * 40 + sc8] = o8;
    }
    __syncthreads();
  }

  // epilogue: C layout row=(lane>>4)*4+r, col=lane&15
  #pragma unroll
  for (int i = 0; i < 3; ++i) {
    int o = uo[i], nt = unt[i];
    #pragma unroll
    for (int mt = 0; mt < 4; ++mt)
      #pragma unroll
      for (int r = 0; r < 4; ++r) {
        int row  = mh + mt * 16 + lk * 4 + r;       // token
        int dcol = nt * 16 + lr;                    // d within 32
        float v = acc[i][mt][r];
        if (o >= 3) v += posW[row * 768 + (o - 3) * 256 + h * 32 + dcol];
        if (o == 2)      VsT[dcol * 136 + row] = f2bf(v);
        else if (o == 5) VmT[dcol * 136 + row] = f2bf(v);
        else {
          unsigned short* Qb = (o == 0) ? Qs : (o == 1) ? Ks : (o == 3) ? Qm : Km;
          Qb[row * 40 + dcol] = f2bf(v);
        }
      }
  }
  __syncthreads();   // QKV visible; PX free for P use

  unsigned short* P = PX;                           // [128][40], 32-key chunks
  const int m0 = w * 16;

  // ======== Phase B: self attention (128 keys, +bias) ========
  {
    f32x4 sc[8];
    bf16x8 qa = *(const bf16x8*)&Qs[(m0 + lr) * 40 + lk * 8];
    __builtin_amdgcn_s_setprio(1);
    #pragma unroll
    for (int nf = 0; nf < 8; ++nf) {
      bf16x8 kb = *(const bf16x8*)&Ks[(nf * 16 + lr) * 40 + lk * 8];
      sc[nf] = __builtin_amdgcn_mfma_f32_16x16x32_bf16(qa, kb,
                                                       f32x4{0.f,0.f,0.f,0.f}, 0, 0, 0);
    }
    __builtin_amdgcn_s_setprio(0);
    const float* bt = bias_t + (size_t)h * 16384 + (m0 + lk * 4) * 128;
    float rmax[4] = {-1e30f, -1e30f, -1e30f, -1e30f};
    float rsum[4] = {0.f, 0.f, 0.f, 0.f};
    #pragma unroll
    for (int nf = 0; nf < 8; ++nf)
      #pragma unroll
      for (int r = 0; r < 4; ++r) {
        float v = sc[nf][r] * scale + bt[r * 128 + nf * 16 + lr];
        sc[nf][r] = v;
        rmax[r] = fmaxf(rmax[r], v);
      }
    #pragma unroll
    for (int r = 0; r < 4; ++r) {
      float m = rmax[r];
      #pragma unroll
      for (int d = 1; d < 16; d <<= 1) m = fmaxf(m, __shfl_xor(m, d, 64));
      rmax[r] = m;
    }
    #pragma unroll
    for (int nf = 0; nf < 8; ++nf)
      #pragma unroll
      for (int r = 0; r < 4; ++r) {
        float p = __expf(sc[nf][r] - rmax[r]);
        rsum[r] += p;
        sc[nf][r] = p;
      }
    float rs[4];
    #pragma unroll
    for (int r = 0; r < 4; ++r) {
      float t = rsum[r];
      #pragma unroll
      for (int d = 1; d < 16; d <<= 1) t += __shfl_xor(t, d, 64);
      rs[r] = 1.f / t;
    }
    // PV in 32-key chunks (P rows wave-private; same-wave ds order via lgkmcnt)
    f32x4 oc[2];
    oc[0] = f32x4{0.f,0.f,0.f,0.f}; oc[1] = f32x4{0.f,0.f,0.f,0.f};
    #pragma unroll
    for (int c = 0; c < 4; ++c) {
      #pragma unroll
      for (int nf2 = 0; nf2 < 2; ++nf2)
        #pragma unroll
        for (int r = 0; r < 4; ++r)
          P[(m0 + lk * 4 + r) * 40 + nf2 * 16 + lr] = f2bf(sc[c * 2 + nf2][r]);
      bf16x8 pa = *(const bf16x8*)&P[(m0 + lr) * 40 + lk * 8];
      #pragma unroll
      for (int nt = 0; nt < 2; ++nt) {
        bf16x8 vb = *(const bf16x8*)&VsT[(nt * 16 + lr) * 136 + c * 32 + lk * 8];
        oc[nt] = __builtin_amdgcn_mfma_f32_16x16x32_bf16(pa, vb, oc[nt], 0, 0, 0);
      }
    }
    #pragma unroll
    for (int nt = 0; nt < 2; ++nt)
      #pragma unroll
      for (int r = 0; r < 4; ++r) {
        size_t row = (size_t)b * 128 + m0 + lk * 4 + r;
        xcat[row * 512 + 256 + h * 32 + nt * 16 + lr] = f2bf(oc[nt][r] * rs[r]);
      }
  }

  // ======== Phase C: mutual attention (half swap, 64 keys, no bias) ========
  {
    const int q0   = (w < 4) ? 64 + m0 : m0 - 64;  // out rows 0..63 use q2; 64..127 q1
    const int koff = (w < 4) ? 0 : 64;             // k1/v1 vs k2/v2
    f32x4 sc2[4];
    bf16x8 qa = *(const bf16x8*)&Qm[(q0 + lr) * 40 + lk * 8];
    __builtin_amdgcn_s_setprio(1);
    #pragma unroll
    for (int nf = 0; nf < 4; ++nf) {
      bf16x8 kb = *(const bf16x8*)&Km[(koff + nf * 16 + lr) * 40 + lk * 8];
      sc2[nf] = __builtin_amdgcn_mfma_f32_16x16x32_bf16(qa, kb,
                                                        f32x4{0.f,0.f,0.f,0.f}, 0, 0, 0);
    }
    __builtin_amdgcn_s_setprio(0);
    float rmax2[4] = {-1e30f, -1e30f, -1e30f, -1e30f};
    float rsum2[4] = {0.f, 0.f, 0.f, 0.f};
    #pragma unroll
    for (int nf = 0; nf < 4; ++nf)
      #pragma unroll
      for (int r = 0; r < 4; ++r) {
        float v = sc2[nf][r] * scale;
        sc2[nf][r] = v;
        rmax2[r] = fmaxf(rmax2[r], v);
      }
    #pragma unroll
    for (int r = 0; r < 4; ++r) {
      float m = rmax2[r];
      #pragma unroll
      for (int d = 1; d < 16; d <<= 1) m = fmaxf(m, __shfl_xor(m, d, 64));
      rmax2[r] = m;
    }
    #pragma unroll
    for (int nf = 0; nf < 4; ++nf)
      #pragma unroll
      for (int r = 0; r < 4; ++r) {
        float p = __expf(sc2[nf][r] - rmax2[r]);
        rsum2[r] += p;
        sc2[nf][r] = p;
      }
    float rs2[4];
    #pragma unroll
    for (int r = 0; r < 4; ++r) {
      float t = rsum2[r];
      #pragma unroll
      for (int d = 1; d < 16; d <<= 1) t += __shfl_xor(t, d, 64);
      rs2[r] = 1.f / t;
    }
    f32x4 oc[2];
    oc[0] = f32x4{0.f,0.f,0.f,0.f}; oc[1] = f32x4{0.f,0.f,0.f,0.f};
    #pragma unroll
    for (int c = 0; c < 2; ++c) {
      #pragma unroll
      for (int nf2 = 0; nf2 < 2; ++nf2)
        #pragma unroll
        for (int r = 0; r < 4; ++r)
          P[(m0 + lk * 4 + r) * 40 + nf2 * 16 + lr] = f2bf(sc2[c * 2 + nf2][r]);
      bf16x8 pa = *(const bf16x8*)&P[(m0 + lr) * 40 + lk * 8];
      #pragma unroll
      for (int nt = 0; nt < 2; ++nt) {
        bf16x8 vb = *(const bf16x8*)&VmT[(nt * 16 + lr) * 136 + koff + c * 32 + lk * 8];
        oc[nt] = __builtin_amdgcn_mfma_f32_16x16x32_bf16(pa, vb, oc[nt], 0, 0, 0);
      }
    }
    #pragma unroll
    for (int nt = 0; nt < 2; ++nt)
      #pragma unroll
      for (int r = 0; r < 4; ++r) {
        size_t row = (size_t)b * 128 + m0 + lk * 4 + r;
        xcat[row * 512 + h * 32 + nt * 16 + lr] = f2bf(oc[nt][r] * rs2[r]);
      }
  }
}

// ---------------- in-place projection GEMM (unchanged, at BW roofline) ----------
// out[262144][256] f32 = xcat[262144][512] bf16 @ Wpb[256][512]^T + bp.
// xcat and out alias (d_out); row-tiles are block-exclusive.

__global__ __launch_bounds__(512, 2) void proj_kernel(
    const unsigned short* __restrict__ xcat,
    const unsigned short* __restrict__ Wpb,
    const float* __restrict__ bp,
    float* __restrict__ out)
{
  __shared__ unsigned short Alds[2][128 * 64];     // 2 x 16 KB
  __shared__ unsigned short Blds[2][256 * 64];     // 2 x 32 KB

  const int tid = threadIdx.x, w = tid >> 6, lane = tid & 63;
  const int lr = lane & 15, lk = lane >> 4;
  const int wr = w >> 2, wc = w & 3;               // 2 x 4 wave grid
  const size_t m0 = (size_t)blockIdx.x * 128;

  f32x4 acc[4][4];
  #pragma unroll
  for (int i = 0; i < 4; ++i)
    #pragma unroll
    for (int j = 0; j < 4; ++j) acc[i][j] = f32x4{0.f, 0.f, 0.f, 0.f};

  auto stage = [&](int buf, int k0) {
    #pragma unroll
    for (int i = 0; i < 2; ++i) {                  // A: 128 x 64 bf16
      int L = (i * 512 + tid) * 16;
      int row = L >> 7;
      int inrow = (L & 127) ^ ((row & 7) << 4);
      gload_lds16((const char*)xcat + (m0 + row) * 1024 + k0 * 2 + inrow,
                  (char*)&Alds[buf][0] + L);
    }
    #pragma unroll
    for (int i = 0; i < 4; ++i) {                  // B: 256 x 64 bf16
      int L = (i * 512 + tid) * 16;
      int row = L >> 7;
      int inrow = (L & 127) ^ ((row & 7) << 4);
      gload_lds16((const char*)Wpb + (size_t)row * 1024 + k0 * 2 + inrow,
                  (char*)&Blds[buf][0] + L);
    }
  };

  stage(0, 0);
  __syncthreads();
  int cur = 0;
  for (int t = 0; t < 8; ++t) {
    if (t < 7) stage(cur ^ 1, (t + 1) * 64);
    const char* At = (const char*)&Alds[cur][0];
    const char* Bt = (const char*)&Blds[cur][0];
    #pragma unroll
    for (int kk = 0; kk < 2; ++kk) {
      bf16x8 af[4], bfr[4];
      #pragma unroll
      for (int mt = 0; mt < 4; ++mt) {
        int row = wr * 64 + mt * 16 + lr;
        int off = (row * 128 + kk * 64 + lk * 16) ^ ((row & 7) << 4);
        af[mt] = *(const bf16x8*)(At + off);
      }
      #pragma unroll
      for (int nt = 0; nt < 4; ++nt) {
        int row = wc * 64 + nt * 16 + lr;
        int off = (row * 128 + kk * 64 + lk * 16) ^ ((row & 7) << 4);
        bfr[nt] = *(const bf16x8*)(Bt + off);
      }
      #pragma unroll
      for (int mt = 0; mt < 4; ++mt)
        #pragma unroll
        for (int nt = 0; nt < 4; ++nt)
          acc[mt][nt] = __builtin_amdgcn_mfma_f32_16x16x32_bf16(af[mt], bfr[nt],
                                                                acc[mt][nt], 0, 0, 0);
    }
    __syncthreads();
    cur ^= 1;
  }

  #pragma unroll
  for (int mt = 0; mt < 4; ++mt)
    #pragma unroll
    for (int r = 0; r < 4; ++r) {
      size_t grow = m0 + wr * 64 + mt * 16 + lk * 4 + r;
      #pragma unroll
      for (int nt = 0; nt < 4; ++nt) {
        int gcol = wc * 64 + nt * 16 + lr;
        out[grow * 256 + gcol] = acc[mt][nt][r] + bp[gcol];
      }
    }
}

// ---------------- launch ----------------

extern "C" void kernel_launch(void* const* d_in, const int* in_sizes, int n_in,
                              void* d_out, int out_size, void* d_ws, size_t ws_size,
                              hipStream_t stream) {
  (void)in_sizes; (void)n_in; (void)out_size;
  const float* x   = (const float*)d_in[0];
  const float* rpb = (const float*)d_in[1];
  const float* Wqs = (const float*)d_in[2];
  const float* Wqm = (const float*)d_in[3];
  const float* Wp  = (const float*)d_in[4];
  const float* bp  = (const float*)d_in[5];
  char* ws = (char*)d_ws;

  // workspace: tables only (2,097,152 bytes)
  size_t off = 0;
  float* pos_t  = (float*)(ws + off); off += 32768ull  * 4;
  float* posW   = (float*)(ws + off); off += 98304ull  * 4;
  float* bias_t = (float*)(ws + off); off += 131072ull * 4;
  unsigned short* Wsb = (unsigned short*)(ws + off); off += 196608ull * 2;
  unsigned short* Wmb = (unsigned short*)(ws + off); off += 196608ull * 2;
  unsigned short* Wpb = (unsigned short*)(ws + off); off += 131072ull * 2;
  if (ws_size < off) return;                        // 2 MB — should always fit

  // xcat (bf16 [262144][512] = 268,435,456 B) lives in d_out; proj runs in-place.
  unsigned short* xcat = (unsigned short*)d_out;

  pos_kernel <<<dim3(128),  dim3(256), 0, stream>>>(pos_t);
  bias_kernel<<<dim3(512),  dim3(256), 0, stream>>>(rpb, bias_t);
  wconv_kernel<<<dim3(2048), dim3(256), 0, stream>>>(Wqs, Wqm, Wp, Wsb, Wmb, Wpb);
  posw_kernel<<<dim3(384),  dim3(256), 0, stream>>>(pos_t, Wqm, posW);

  fused_head<<<dim3(16384), dim3(512), 0, stream>>>(x, Wsb, Wmb, posW, bias_t, xcat);

  proj_kernel<<<dim3(2048), dim3(512), 0, stream>>>(xcat, Wpb, bp, (float*)d_out);
}